// Round 2
// baseline (1040.847 us; speedup 1.0000x reference)
//
#include <hip/hip_runtime.h>

#define BLOCK 256
#define CHUNK 8

__device__ __forceinline__ float leaky_(float x){ return x >= 0.f ? x : 0.01f*x; }

// ---------------- Kernel A: per-structure precompute ----------------
// ci_out[s*12 + 0..8]  = inv(cell[s]) row-major
// cc_out[s*32 + k]     = b2a[k] + sum_{j1,j2} cr[j1]*cr[j2]*w2a[k][9 + j1*9 + j2]
__global__ void prep_kernel(const float* __restrict__ cell,
                            const float* __restrict__ w2a,
                            const float* __restrict__ b2a,
                            float* __restrict__ ci_out,
                            float* __restrict__ cc_out,
                            int S)
{
    int gid = blockIdx.x * blockDim.x + threadIdx.x;
    int s = gid >> 5;
    if (s >= S) return;
    int k = gid & 31;

    float cr[9];
    #pragma unroll
    for (int j = 0; j < 9; j++) cr[j] = cell[s*9 + j];

    if (k == 0) {
        float a=cr[0],b=cr[1],c=cr[2],d=cr[3],e=cr[4],f=cr[5],g=cr[6],h=cr[7],i=cr[8];
        float A = e*i - f*h;
        float B = f*g - d*i;
        float C = d*h - e*g;
        float det = a*A + b*B + c*C;
        float r = 1.0f / det;
        float* o = ci_out + s*12;
        o[0] = A*r;         o[1] = (c*h - b*i)*r; o[2] = (b*f - c*e)*r;
        o[3] = B*r;         o[4] = (a*i - c*g)*r; o[5] = (c*d - a*f)*r;
        o[6] = C*r;         o[7] = (b*g - a*h)*r; o[8] = (a*e - b*d)*r;
    }

    float acc = b2a[k];
    const float* wr = w2a + k*90 + 9;
    #pragma unroll
    for (int j1 = 0; j1 < 9; j1++) {
        float c1 = cr[j1];
        #pragma unroll
        for (int j2 = 0; j2 < 9; j2++)
            acc = fmaf(c1 * cr[j2], wr[j1*9 + j2], acc);
    }
    cc_out[s*32 + k] = acc;
}

// ---------------- Kernel B: per-atom MLP + segment sum ----------------
// LDS layout (floats):
//   [0,288)   w2a9T[j][k] = w2a[k*90+j]   (j<9,k<32)  float4 idx j*8+k4
//   [288,800) w2bT[k][m]  = w2b[m*32+k]   (k<32,m<16) float4 idx 72+k*4+m4
//   [800,928) w2cT[m][p]  = w2c[p*16+m], pad p<8      float4 idx 200+m*2+p4
//   [928,944) b2b
//   [944,952) b2c (pad 8)
//   [952,964) w0 rows packed (w,w,w,b)  float4 idx 238..240
//   [964,976) w1 rows packed            float4 idx 241..243
//   [976,988) w1n rows packed           float4 idx 244..246
__device__ __forceinline__ void compute_h9(
    float px, float py, float pz, float ax, float ay, float az,
    const float* ci, const float4* lds4, float* h9)
{
    float f0 = fmaf(px, ci[0], fmaf(py, ci[3], pz*ci[6]));
    float f1 = fmaf(px, ci[1], fmaf(py, ci[4], pz*ci[7]));
    float f2 = fmaf(px, ci[2], fmaf(py, ci[5], pz*ci[8]));
    float t0 = f0 - floorf(f0) - 0.5f;
    float t1 = f1 - floorf(f1) - 0.5f;
    float t2 = f2 - floorf(f2) - 0.5f;

    h9[0] = ax; h9[1] = ay; h9[2] = az;

    #pragma unroll
    for (int r = 0; r < 3; r++) {
        float4 q0 = lds4[238 + r];
        float ap3 = leaky_(fmaf(ax, q0.x, fmaf(ay, q0.y, fmaf(az, q0.z, q0.w))));
        float4 q1 = lds4[241 + r];
        float d1  = fmaf(t0, q1.x, fmaf(t1, q1.y, fmaf(t2, q1.z, q1.w)));
        float4 q2 = lds4[244 + r];
        float d2  = q2.w - fmaf(t0, q2.x, fmaf(t1, q2.y, t2*q2.z));
        h9[3+r] = fmaxf(d1, 0.f) * ap3;
        h9[6+r] = fmaxf(d2, 0.f) * ap3;
    }
}

__global__ __launch_bounds__(BLOCK, 4)
void main_kernel(const float* __restrict__ atom_prop,
                 const float* __restrict__ pos,
                 const int*   __restrict__ batch,
                 const float* __restrict__ w0,  const float* __restrict__ b0,
                 const float* __restrict__ w1,  const float* __restrict__ b1,
                 const float* __restrict__ w1n, const float* __restrict__ b1n,
                 const float* __restrict__ w2a,
                 const float* __restrict__ w2b, const float* __restrict__ b2b,
                 const float* __restrict__ w2c, const float* __restrict__ b2c,
                 const float* __restrict__ ci_ws,
                 const float* __restrict__ cc_ws,
                 float* __restrict__ out,
                 int N)
{
    __shared__ float lds[988];
    int tid = threadIdx.x;
    for (int t = tid; t < 288; t += BLOCK) { int j = t >> 5, k = t & 31; lds[t] = w2a[k*90 + j]; }
    for (int t = tid; t < 512; t += BLOCK) { int k = t >> 4, m = t & 15; lds[288 + t] = w2b[m*32 + k]; }
    if (tid < 128) { int m = tid >> 3, p = tid & 7; lds[800 + tid] = (p < 6) ? w2c[p*16 + m] : 0.f; }
    if (tid < 16) lds[928 + tid] = b2b[tid];
    if (tid < 8)  lds[944 + tid] = (tid < 6) ? b2c[tid] : 0.f;
    if (tid < 12) { int r = tid >> 2, c = tid & 3; lds[952 + tid] = (c < 3) ? w0[r*3 + c]  : b0[r];  }
    if (tid < 12) { int r = tid >> 2, c = tid & 3; lds[964 + tid] = (c < 3) ? w1[r*3 + c]  : b1[r];  }
    if (tid < 12) { int r = tid >> 2, c = tid & 3; lds[976 + tid] = (c < 3) ? w1n[r*3 + c] : b1n[r]; }
    __syncthreads();

    const float4* lds4 = (const float4*)lds;

    int base = (blockIdx.x * BLOCK + tid) * CHUNK;

    float acc[6] = {0.f,0.f,0.f,0.f,0.f,0.f};
    int cur_s = -1;
    float ci[9];

    for (int t = 0; t < CHUNK; t += 2) {
        int i = base + t;
        if (i >= N) break;
        bool hasB = (i + 1 < N);

        int sA, sB = -1;
        float pxA,pyA,pzA,pxB=0,pyB=0,pzB=0;
        float axA,ayA,azA,axB=0,ayB=0,azB=0;
        if (hasB) {
            int2 bb = *(const int2*)(batch + i);
            sA = bb.x; sB = bb.y;
            float2 p0 = *(const float2*)(pos + 3*i);
            float2 p1 = *(const float2*)(pos + 3*i + 2);
            float2 p2 = *(const float2*)(pos + 3*i + 4);
            pxA = p0.x; pyA = p0.y; pzA = p1.x; pxB = p1.y; pyB = p2.x; pzB = p2.y;
            float2 a0 = *(const float2*)(atom_prop + 3*i);
            float2 a1 = *(const float2*)(atom_prop + 3*i + 2);
            float2 a2 = *(const float2*)(atom_prop + 3*i + 4);
            axA = a0.x; ayA = a0.y; azA = a1.x; axB = a1.y; ayB = a2.x; azB = a2.y;
        } else {
            sA = batch[i];
            pxA = pos[3*i]; pyA = pos[3*i+1]; pzA = pos[3*i+2];
            axA = atom_prop[3*i]; ayA = atom_prop[3*i+1]; azA = atom_prop[3*i+2];
        }

        bool aSep = false;
        if (sA != cur_s) {
            if (cur_s >= 0) {
                #pragma unroll
                for (int p = 0; p < 6; p++) atomicAdd(out + cur_s*6 + p, acc[p]);
            }
            cur_s = sA;
            #pragma unroll
            for (int j = 0; j < 9; j++) ci[j] = ci_ws[sA*12 + j];
            #pragma unroll
            for (int p = 0; p < 6; p++) acc[p] = 0.f;
        }

        float h9A[9];
        compute_h9(pxA,pyA,pzA, axA,ayA,azA, ci, lds4, h9A);

        if (hasB && sB != cur_s) {
            #pragma unroll
            for (int p = 0; p < 6; p++) atomicAdd(out + cur_s*6 + p, acc[p]);
            aSep = true;
            cur_s = sB;
            #pragma unroll
            for (int j = 0; j < 9; j++) ci[j] = ci_ws[sB*12 + j];
            #pragma unroll
            for (int p = 0; p < 6; p++) acc[p] = 0.f;
        }

        float h9B[9];
        if (hasB) {
            compute_h9(pxB,pyB,pzB, axB,ayB,azB, ci, lds4, h9B);
        } else {
            #pragma unroll
            for (int j = 0; j < 9; j++) h9B[j] = 0.f;
        }

        const float4* ccA = (const float4*)(cc_ws + (size_t)sA*32);
        const float4* ccB = (const float4*)(cc_ws + (size_t)(hasB ? sB : sA)*32);

        // ---- fused L1 (9->32) + relu + L2 (32->16), k in blocks of 4 ----
        float vA[16], vB[16];
        #pragma unroll
        for (int m = 0; m < 16; m++) { float b = lds[928 + m]; vA[m] = b; vB[m] = b; }

        #pragma unroll
        for (int k4 = 0; k4 < 8; k4++) {
            float4 ua = ccA[k4];
            float4 ub = ccB[k4];
            #pragma unroll
            for (int j = 0; j < 9; j++) {
                float4 w = lds4[j*8 + k4];
                float ha = h9A[j], hb = h9B[j];
                ua.x = fmaf(ha, w.x, ua.x); ua.y = fmaf(ha, w.y, ua.y);
                ua.z = fmaf(ha, w.z, ua.z); ua.w = fmaf(ha, w.w, ua.w);
                ub.x = fmaf(hb, w.x, ub.x); ub.y = fmaf(hb, w.y, ub.y);
                ub.z = fmaf(hb, w.z, ub.z); ub.w = fmaf(hb, w.w, ub.w);
            }
            float as0 = fmaxf(ua.x, 0.f), as1 = fmaxf(ua.y, 0.f), as2 = fmaxf(ua.z, 0.f), as3 = fmaxf(ua.w, 0.f);
            float bs0 = fmaxf(ub.x, 0.f), bs1 = fmaxf(ub.y, 0.f), bs2 = fmaxf(ub.z, 0.f), bs3 = fmaxf(ub.w, 0.f);
            float as[4] = {as0, as1, as2, as3};
            float bs[4] = {bs0, bs1, bs2, bs3};
            #pragma unroll
            for (int c = 0; c < 4; c++) {
                float ua_s = as[c], ub_s = bs[c];
                int k = 4*k4 + c;
                #pragma unroll
                for (int m4 = 0; m4 < 4; m4++) {
                    float4 w = lds4[72 + k*4 + m4];
                    vA[4*m4+0] = fmaf(ua_s, w.x, vA[4*m4+0]);
                    vA[4*m4+1] = fmaf(ua_s, w.y, vA[4*m4+1]);
                    vA[4*m4+2] = fmaf(ua_s, w.z, vA[4*m4+2]);
                    vA[4*m4+3] = fmaf(ua_s, w.w, vA[4*m4+3]);
                    vB[4*m4+0] = fmaf(ub_s, w.x, vB[4*m4+0]);
                    vB[4*m4+1] = fmaf(ub_s, w.y, vB[4*m4+1]);
                    vB[4*m4+2] = fmaf(ub_s, w.z, vB[4*m4+2]);
                    vB[4*m4+3] = fmaf(ub_s, w.w, vB[4*m4+3]);
                }
            }
        }

        #pragma unroll
        for (int m = 0; m < 16; m++) { vA[m] = leaky_(vA[m]); vB[m] = leaky_(vB[m]); }

        // ---- L3: 16 -> 6 (padded to 8) ----
        float oA[8], oB[8];
        #pragma unroll
        for (int p = 0; p < 8; p++) { float b = lds[944 + p]; oA[p] = b; oB[p] = b; }
        #pragma unroll
        for (int m = 0; m < 16; m++) {
            float va = vA[m], vb = vB[m];
            #pragma unroll
            for (int p4 = 0; p4 < 2; p4++) {
                float4 w = lds4[200 + m*2 + p4];
                oA[4*p4+0] = fmaf(va, w.x, oA[4*p4+0]);
                oA[4*p4+1] = fmaf(va, w.y, oA[4*p4+1]);
                oA[4*p4+2] = fmaf(va, w.z, oA[4*p4+2]);
                oA[4*p4+3] = fmaf(va, w.w, oA[4*p4+3]);
                oB[4*p4+0] = fmaf(vb, w.x, oB[4*p4+0]);
                oB[4*p4+1] = fmaf(vb, w.y, oB[4*p4+1]);
                oB[4*p4+2] = fmaf(vb, w.z, oB[4*p4+2]);
                oB[4*p4+3] = fmaf(vb, w.w, oB[4*p4+3]);
            }
        }

        if (aSep) {
            #pragma unroll
            for (int p = 0; p < 6; p++) atomicAdd(out + sA*6 + p, oA[p]);
        } else {
            #pragma unroll
            for (int p = 0; p < 6; p++) acc[p] += oA[p];
        }
        if (hasB) {
            #pragma unroll
            for (int p = 0; p < 6; p++) acc[p] += oB[p];
        }
    }

    if (cur_s >= 0) {
        #pragma unroll
        for (int p = 0; p < 6; p++) atomicAdd(out + cur_s*6 + p, acc[p]);
    }
}

extern "C" void kernel_launch(void* const* d_in, const int* in_sizes, int n_in,
                              void* d_out, int out_size, void* d_ws, size_t ws_size,
                              hipStream_t stream)
{
    const float* atom_prop = (const float*)d_in[0];
    const float* pos       = (const float*)d_in[1];
    const float* cell      = (const float*)d_in[2];
    const int*   batch     = (const int*)  d_in[3];
    const float* w0  = (const float*)d_in[4];
    const float* b0  = (const float*)d_in[5];
    const float* w1  = (const float*)d_in[6];
    const float* b1  = (const float*)d_in[7];
    const float* w1n = (const float*)d_in[8];
    const float* b1n = (const float*)d_in[9];
    const float* w2a = (const float*)d_in[10];
    const float* b2a = (const float*)d_in[11];
    const float* w2b = (const float*)d_in[12];
    const float* b2b = (const float*)d_in[13];
    const float* w2c = (const float*)d_in[14];
    const float* b2c = (const float*)d_in[15];

    int N = in_sizes[3];          // batch has one entry per atom
    int S = in_sizes[2] / 9;      // cell is [S,3,3]

    float* out   = (float*)d_out;
    float* ci_ws = (float*)d_ws;                 // [S,12]
    float* cc_ws = (float*)d_ws + (size_t)S*12;  // [S,32]

    hipMemsetAsync(d_out, 0, (size_t)out_size * sizeof(float), stream);

    int prep_threads = S * 32;
    prep_kernel<<<(prep_threads + 255)/256, 256, 0, stream>>>(cell, w2a, b2a, ci_ws, cc_ws, S);

    int total_threads = (N + CHUNK - 1) / CHUNK;
    int grid = (total_threads + BLOCK - 1) / BLOCK;
    main_kernel<<<grid, BLOCK, 0, stream>>>(atom_prop, pos, batch,
                                            w0, b0, w1, b1, w1n, b1n,
                                            w2a, w2b, b2b, w2c, b2c,
                                            ci_ws, cc_ws, out, N);
}

// Round 3
// 278.231 us; speedup vs baseline: 3.7410x; 3.7410x over previous
//
#include <hip/hip_runtime.h>

#define BLOCK 256
#define CHUNK 8

__device__ __forceinline__ float leaky_(float x){ return x >= 0.f ? x : 0.01f*x; }

// ---------------- Kernel A: per-structure precompute + weight transposes ----
// ws layout (floats):
//   ci_ws  [S*12]          : inv(cell) row-major, padded to 12
//   cc_ws  [S*32]          : b2a[k] + cell_ravel @ w2a[:,9:].T  (cell part of L1)
//   w2bT   [512]  (k*16+m) : transposed L2 weights, contiguous per k
//   w2cT   [128]  (m*8+p)  : transposed L3 weights, contiguous per m, pad 8
__global__ void prep_kernel(const float* __restrict__ cell,
                            const float* __restrict__ w2a,
                            const float* __restrict__ b2a,
                            const float* __restrict__ w2b,
                            const float* __restrict__ w2c,
                            float* __restrict__ ci_out,
                            float* __restrict__ cc_out,
                            float* __restrict__ w2bT,
                            float* __restrict__ w2cT,
                            int S)
{
    int gid = blockIdx.x * blockDim.x + threadIdx.x;

    if (gid < 512) { int k = gid >> 4, m = gid & 15; w2bT[k*16 + m] = w2b[m*32 + k]; }
    if (gid < 128) { int m = gid >> 3, p = gid & 7;  w2cT[m*8 + p] = (p < 6) ? w2c[p*16 + m] : 0.f; }

    int s = gid >> 5;
    if (s >= S) return;
    int k = gid & 31;

    float cr[9];
    #pragma unroll
    for (int j = 0; j < 9; j++) cr[j] = cell[s*9 + j];

    if (k == 0) {
        float a=cr[0],b=cr[1],c=cr[2],d=cr[3],e=cr[4],f=cr[5],g=cr[6],h=cr[7],i=cr[8];
        float A = e*i - f*h;
        float B = f*g - d*i;
        float C = d*h - e*g;
        float det = a*A + b*B + c*C;
        float r = 1.0f / det;
        float* o = ci_out + s*12;
        o[0] = A*r;         o[1] = (c*h - b*i)*r; o[2] = (b*f - c*e)*r;
        o[3] = B*r;         o[4] = (a*i - c*g)*r; o[5] = (c*d - a*f)*r;
        o[6] = C*r;         o[7] = (b*g - a*h)*r; o[8] = (a*e - b*d)*r;
        o[9] = 0.f; o[10] = 0.f; o[11] = 0.f;
    }

    float acc = b2a[k];
    const float* wr = w2a + k*90 + 9;
    #pragma unroll
    for (int j1 = 0; j1 < 9; j1++) {
        float c1 = cr[j1];
        #pragma unroll
        for (int j2 = 0; j2 < 9; j2++)
            acc = fmaf(c1 * cr[j2], wr[j1*9 + j2], acc);
    }
    cc_out[s*32 + k] = acc;
}

// ---------------- Kernel B: per-atom MLP + segment sum ----------------
// All weights are read with wave-uniform indices from __restrict__ const
// pointers -> compiler emits s_load (SGPR operands for the FMAs). No LDS.
__global__ __launch_bounds__(BLOCK)
void main_kernel(const float* __restrict__ atom_prop,
                 const float* __restrict__ pos,
                 const int*   __restrict__ batch,
                 const float* __restrict__ w0,  const float* __restrict__ b0,
                 const float* __restrict__ w1,  const float* __restrict__ b1,
                 const float* __restrict__ w1n, const float* __restrict__ b1n,
                 const float* __restrict__ w2a,
                 const float* __restrict__ b2b,
                 const float* __restrict__ b2c,
                 const float* __restrict__ ci_ws,
                 const float* __restrict__ cc_ws,
                 const float* __restrict__ w2bT,
                 const float* __restrict__ w2cT,
                 float* __restrict__ out,
                 int N)
{
    int lane_id = blockIdx.x * BLOCK + threadIdx.x;
    long long base = (long long)lane_id * CHUNK;
    if (base >= N) return;

    // N is a multiple of CHUNK for this problem; guard stays for safety.
    int bvals[CHUNK];
    if (base + CHUNK <= N) {
        int4 b0_ = *(const int4*)(batch + base);
        int4 b1_ = *(const int4*)(batch + base + 4);
        bvals[0]=b0_.x; bvals[1]=b0_.y; bvals[2]=b0_.z; bvals[3]=b0_.w;
        bvals[4]=b1_.x; bvals[5]=b1_.y; bvals[6]=b1_.z; bvals[7]=b1_.w;
    } else {
        #pragma unroll
        for (int t = 0; t < CHUNK; t++) bvals[t] = (base + t < N) ? batch[base + t] : -1;
    }

    float acc[6] = {0.f,0.f,0.f,0.f,0.f,0.f};
    int cur_s = -1;
    float ci[9];

    #pragma unroll
    for (int t = 0; t < CHUNK; t++) {
        long long i = base + t;
        if (i >= N) break;
        int s = bvals[t];

        if (s != cur_s) {
            if (cur_s >= 0) {
                #pragma unroll
                for (int p = 0; p < 6; p++) atomicAdd(out + cur_s*6 + p, acc[p]);
                #pragma unroll
                for (int p = 0; p < 6; p++) acc[p] = 0.f;
            }
            cur_s = s;
            const float4* cip = (const float4*)(ci_ws + (size_t)s*12);
            float4 c0 = cip[0], c1 = cip[1], c2 = cip[2];
            ci[0]=c0.x; ci[1]=c0.y; ci[2]=c0.z; ci[3]=c0.w;
            ci[4]=c1.x; ci[5]=c1.y; ci[6]=c1.z; ci[7]=c1.w;
            ci[8]=c2.x;
        }

        float px = pos[3*i], py = pos[3*i+1], pz = pos[3*i+2];
        float ax = atom_prop[3*i], ay = atom_prop[3*i+1], az = atom_prop[3*i+2];

        // ---- h9 ----
        float f0 = fmaf(px, ci[0], fmaf(py, ci[3], pz*ci[6]));
        float f1 = fmaf(px, ci[1], fmaf(py, ci[4], pz*ci[7]));
        float f2 = fmaf(px, ci[2], fmaf(py, ci[5], pz*ci[8]));
        float t0 = f0 - floorf(f0) - 0.5f;
        float t1 = f1 - floorf(f1) - 0.5f;
        float t2 = f2 - floorf(f2) - 0.5f;

        float h9[9];
        h9[0] = ax; h9[1] = ay; h9[2] = az;
        #pragma unroll
        for (int r = 0; r < 3; r++) {
            float ap3 = leaky_(fmaf(ax, w0[r*3+0], fmaf(ay, w0[r*3+1], fmaf(az, w0[r*3+2], b0[r]))));
            float d1  = fmaf(t0, w1[r*3+0],  fmaf(t1, w1[r*3+1],  fmaf(t2, w1[r*3+2], b1[r])));
            float d2  = b1n[r] - fmaf(t0, w1n[r*3+0], fmaf(t1, w1n[r*3+1], t2*w1n[r*3+2]));
            h9[3+r] = fmaxf(d1, 0.f) * ap3;
            h9[6+r] = fmaxf(d2, 0.f) * ap3;
        }

        // ---- fused L1 (9->32) + relu + L2 (32->16), u never materialized ----
        float v[16];
        #pragma unroll
        for (int m = 0; m < 16; m++) v[m] = b2b[m];

        const float4* ccp = (const float4*)(cc_ws + (size_t)s*32);
        #pragma unroll
        for (int k4 = 0; k4 < 8; k4++) {
            float4 c4 = ccp[k4];
            float cc_k[4] = {c4.x, c4.y, c4.z, c4.w};
            #pragma unroll
            for (int c = 0; c < 4; c++) {
                int k = 4*k4 + c;
                float u = cc_k[c];
                const float* wa = w2a + k*90;          // uniform -> s_load
                #pragma unroll
                for (int j = 0; j < 9; j++) u = fmaf(h9[j], wa[j], u);
                u = fmaxf(u, 0.f);
                const float* wb = w2bT + k*16;         // uniform -> s_load_dwordx16
                #pragma unroll
                for (int m = 0; m < 16; m++) v[m] = fmaf(u, wb[m], v[m]);
            }
        }

        #pragma unroll
        for (int m = 0; m < 16; m++) v[m] = leaky_(v[m]);

        // ---- L3: 16 -> 6 ----
        float o[6];
        #pragma unroll
        for (int p = 0; p < 6; p++) o[p] = b2c[p];
        #pragma unroll
        for (int m = 0; m < 16; m++) {
            const float* wc = w2cT + m*8;              // uniform -> s_load
            float vm = v[m];
            #pragma unroll
            for (int p = 0; p < 6; p++) o[p] = fmaf(vm, wc[p], o[p]);
        }

        #pragma unroll
        for (int p = 0; p < 6; p++) acc[p] += o[p];
    }

    if (cur_s >= 0) {
        #pragma unroll
        for (int p = 0; p < 6; p++) atomicAdd(out + cur_s*6 + p, acc[p]);
    }
}

extern "C" void kernel_launch(void* const* d_in, const int* in_sizes, int n_in,
                              void* d_out, int out_size, void* d_ws, size_t ws_size,
                              hipStream_t stream)
{
    const float* atom_prop = (const float*)d_in[0];
    const float* pos       = (const float*)d_in[1];
    const float* cell      = (const float*)d_in[2];
    const int*   batch     = (const int*)  d_in[3];
    const float* w0  = (const float*)d_in[4];
    const float* b0  = (const float*)d_in[5];
    const float* w1  = (const float*)d_in[6];
    const float* b1  = (const float*)d_in[7];
    const float* w1n = (const float*)d_in[8];
    const float* b1n = (const float*)d_in[9];
    const float* w2a = (const float*)d_in[10];
    const float* b2a = (const float*)d_in[11];
    const float* w2b = (const float*)d_in[12];
    const float* b2b = (const float*)d_in[13];
    const float* w2c = (const float*)d_in[14];
    const float* b2c = (const float*)d_in[15];

    int N = in_sizes[3];          // batch has one entry per atom
    int S = in_sizes[2] / 9;      // cell is [S,3,3]

    float* out   = (float*)d_out;
    float* ci_ws = (float*)d_ws;                         // [S*12]
    float* cc_ws = ci_ws + (size_t)S*12;                 // [S*32]
    float* w2bT  = cc_ws + (size_t)S*32;                 // [512]
    float* w2cT  = w2bT + 512;                           // [128]

    hipMemsetAsync(d_out, 0, (size_t)out_size * sizeof(float), stream);

    int prep_threads = S * 32;
    prep_kernel<<<(prep_threads + 255)/256, 256, 0, stream>>>(
        cell, w2a, b2a, w2b, w2c, ci_ws, cc_ws, w2bT, w2cT, S);

    long long total_threads = ((long long)N + CHUNK - 1) / CHUNK;
    int grid = (int)((total_threads + BLOCK - 1) / BLOCK);
    main_kernel<<<grid, BLOCK, 0, stream>>>(atom_prop, pos, batch,
                                            w0, b0, w1, b1, w1n, b1n,
                                            w2a, b2b, b2c,
                                            ci_ws, cc_ws, w2bT, w2cT, out, N);
}